// Round 7
// baseline (623.234 us; speedup 1.0000x reference)
//
#include <hip/hip_runtime.h>

#define NN 50000
#define EE 1600000
#define GG 128
#define NC 10

#define SB_N   49      // superbuckets (dst >> 10)
#define SB_PAD 36864   // padded superbucket region (avg 32653)
#define BK_N   782     // 64-node buckets (dst >> 6)
#define BK_PAD 2560    // padded bucket region (avg 2046)
#define CHUNK  4096
#define NBLK1  391     // ceil(EE / CHUNK)
#define SLICES 9       // ceil(SB_PAD / CHUNK)

typedef __attribute__((ext_vector_type(8))) short bf16x8;
typedef __attribute__((ext_vector_type(4))) float f32x4;
typedef unsigned short u16;

__device__ inline u16 f2bf(float x){
  unsigned u = __builtin_bit_cast(unsigned, x);
  u += 0x7fffu + ((u >> 16) & 1u);          // RNE
  return (u16)(u >> 16);
}
__device__ inline float bf2f(u16 u){
  return __builtin_bit_cast(float, ((unsigned)u) << 16);
}

// ---------------- utility ----------------
__global__ void k_zero_int(int* __restrict__ p, int n){
  int i = blockIdx.x * 256 + threadIdx.x;
  if (i < n) p[i] = 0;
}

// ---------------- level-1 scatter: edges -> 49 superbucket regions ----------------
__global__ __launch_bounds__(256) void k_scatL1(const int* __restrict__ srcI, const int* __restrict__ dstI,
                                                int* __restrict__ scur, int* __restrict__ sstg){
  __shared__ int hist[SB_N];
  __shared__ int base[64];
  __shared__ int gadj[SB_N];
  __shared__ unsigned reo[CHUNK];
  int t = threadIdx.x;
  int e0 = blockIdx.x * CHUNK;
  int cnt = EE - e0; if (cnt > CHUNK) cnt = CHUNK;
  if (t < SB_N) hist[t] = 0;
  __syncthreads();
  unsigned p[16]; int rk[16];
  #pragma unroll
  for (int r = 0; r < 16; ++r){
    int i = r * 256 + t;
    if (i < cnt){
      unsigned d = (unsigned)dstI[e0 + i];
      p[r] = (d << 16) | (unsigned)srcI[e0 + i];
      rk[r] = atomicAdd(&hist[d >> 10], 1);
    }
  }
  __syncthreads();
  if (t < 64) base[t] = (t < SB_N) ? hist[t] : 0;
  __syncthreads();
  for (int off = 1; off < 64; off <<= 1){
    int a = (t < 64 && t >= off) ? base[t - off] : 0;
    __syncthreads();
    if (t < 64) base[t] += a;     // inclusive scan
    __syncthreads();
  }
  if (t < SB_N){
    int ex = base[t] - hist[t];   // exclusive
    gadj[t] = atomicAdd(&scur[t], hist[t]) - ex;
  }
  __syncthreads();
  #pragma unroll
  for (int r = 0; r < 16; ++r){
    int i = r * 256 + t;
    if (i < cnt){
      unsigned sb = p[r] >> 26;
      reo[(base[sb] - hist[sb]) + rk[r]] = p[r];
    }
  }
  __syncthreads();
  for (int q = t; q < cnt; q += 256){
    unsigned v = reo[q];
    unsigned sb = v >> 26;
    int off = gadj[sb] + q;       // = gbase + (q - excl)
    if ((unsigned)off < SB_PAD) sstg[sb * SB_PAD + off] = (int)v;
  }
}

// ---------------- level-2 scatter: superbucket -> 16 sub-buckets (64-node) ----------------
__global__ __launch_bounds__(256) void k_scatL2(const int* __restrict__ sstg, const int* __restrict__ scur,
                                                int* __restrict__ bcur, int* __restrict__ bstg){
  __shared__ int hist[16];
  __shared__ int base[16];
  __shared__ int gadj[16];
  __shared__ unsigned reo[CHUNK];
  int t = threadIdx.x;
  int sb = blockIdx.x / SLICES;
  int sl = blockIdx.x % SLICES;
  int ssz = scur[sb]; if (ssz > SB_PAD) ssz = SB_PAD;
  int i0 = sl * CHUNK;
  int cnt = ssz - i0;
  if (cnt <= 0) return;
  if (cnt > CHUNK) cnt = CHUNK;
  if (t < 16) hist[t] = 0;
  __syncthreads();
  unsigned p[16]; int rk[16];
  #pragma unroll
  for (int r = 0; r < 16; ++r){
    int i = r * 256 + t;
    if (i < cnt){
      p[r] = (unsigned)sstg[sb * SB_PAD + i0 + i];
      rk[r] = atomicAdd(&hist[(p[r] >> 22) & 15], 1);
    }
  }
  __syncthreads();
  if (t < 16) base[t] = hist[t];
  __syncthreads();
  for (int off = 1; off < 16; off <<= 1){
    int a = (t < 16 && t >= off) ? base[t - off] : 0;
    __syncthreads();
    if (t < 16) base[t] += a;
    __syncthreads();
  }
  if (t < 16){
    int ex = base[t] - hist[t];
    gadj[t] = atomicAdd(&bcur[sb * 16 + t], hist[t]) - ex;
  }
  __syncthreads();
  #pragma unroll
  for (int r = 0; r < 16; ++r){
    int i = r * 256 + t;
    if (i < cnt){
      unsigned b = (p[r] >> 22) & 15;
      reo[(base[b] - hist[b]) + rk[r]] = p[r];
    }
  }
  __syncthreads();
  for (int q = t; q < cnt; q += 256){
    unsigned v = reo[q];
    unsigned b = (v >> 22) & 15;
    int off = gadj[b] + q;
    if ((unsigned)off < BK_PAD) bstg[(sb * 16 + b) * BK_PAD + off] = (int)v;
  }
}

// ---------------- finalize: per-bucket node grouping -> adj(u16) + ndinfo ----------------
__global__ __launch_bounds__(256) void k_finalize(const int* __restrict__ bstg, const int* __restrict__ bcur,
                                                  u16* __restrict__ adj, int2* __restrict__ ndinfo){
  __shared__ unsigned ebuf[BK_PAD];
  __shared__ int hist[64];
  __shared__ int lrs[64];
  __shared__ int lcur[64];
  int b = blockIdx.x;
  int t = threadIdx.x;
  int bsz = bcur[b]; if (bsz > BK_PAD) bsz = BK_PAD;
  if (t < 64) hist[t] = 0;
  __syncthreads();
  for (int i = t; i < bsz; i += 256){
    unsigned p = (unsigned)bstg[b * BK_PAD + i];
    ebuf[i] = p;
    atomicAdd(&hist[(p >> 16) & 63], 1);
  }
  __syncthreads();
  if (t < 64) lrs[t] = hist[t];
  __syncthreads();
  for (int off = 1; off < 64; off <<= 1){
    int a = (t < 64 && t >= off) ? lrs[t - off] : 0;
    __syncthreads();
    if (t < 64) lrs[t] += a;
    __syncthreads();
  }
  if (t < 64){
    int ex = lrs[t] - hist[t];
    lcur[t] = ex;
    int node = b * 64 + t;
    if (node < NN) ndinfo[node] = make_int2(b * BK_PAD + ex, hist[t]);
  }
  __syncthreads();
  for (int i = t; i < bsz; i += 256){
    unsigned p = ebuf[i];
    int slot = atomicAdd(&lcur[(p >> 16) & 63], 1);
    adj[b * BK_PAD + slot] = (u16)(p & 0xffffu);
  }
}

// ---------------- fused prep: x->bf16 | W->bf16 transposed | BN fold ----------------
__global__ void k_prep(const float* __restrict__ x, const float* __restrict__ W1f, const float* __restrict__ W2f,
                       const float* __restrict__ b1, const float* __restrict__ b2,
                       const float* __restrict__ gma, const float* __restrict__ bta,
                       const float* __restrict__ rmn, const float* __restrict__ rvr,
                       u16* __restrict__ xb, u16* __restrict__ Wt,
                       float* __restrict__ SC, float* __restrict__ SH){
  int bid = blockIdx.x;
  int t = threadIdx.x;
  if (bid < 6250){
    int i = bid * 256 + t;
    float4 v = ((const float4*)x)[i];
    ushort4 o;
    o.x = f2bf(v.x); o.y = f2bf(v.y); o.z = f2bf(v.z); o.w = f2bf(v.w);
    ((ushort4*)xb)[i] = o;
  } else if (bid < 6634){
    int i = (bid - 6250) * 256 + t;       // 0..98303
    int a = i >> 14; int r = i & 16383; int n = r >> 7; int k = r & 127;
    const float* Wsrc = (a < 3) ? (W1f + a * 16384) : (W2f + (a - 3) * 16384);
    Wt[a * 16384 + n * 128 + k] = f2bf(Wsrc[k * 128 + n]);
  } else {
    for (int i = t; i < 768; i += 256){
      int l = i >> 8; int r = i & 255; int mode = r >> 7; int c = r & 127;
      if (mode == 0){
        SC[(l * 2) * 128 + c] = 1.0f;
        SH[(l * 2) * 128 + c] = b1[l * 128 + c];
      } else {
        float S = gma[l * 128 + c] * rsqrtf(rvr[l * 128 + c] + 1e-5f);
        SC[(l * 2 + 1) * 128 + c] = S;
        SH[(l * 2 + 1) * 128 + c] = (b2[l * 128 + c] - rmn[l * 128 + c]) * S + bta[l * 128 + c];
      }
    }
  }
}

// ---------------- aggregation: 16 lanes/node, bf16x8 gathers, 8-deep ----------------
__global__ __launch_bounds__(256) void k_agg(const u16* __restrict__ xb, u16* __restrict__ hb,
                                             const u16* __restrict__ adj,
                                             const int2* __restrict__ ndinfo){
  int t = threadIdx.x;
  int node = blockIdx.x * 16 + (t >> 4);   // grid = 3125 covers NN exactly
  int lane = t & 15;
  const bf16x8* xv = (const bf16x8*)xb;    // 16 bf16x8 per 128-wide row
  bf16x8 sv = xv[(long)node * 16 + lane];
  float a[8];
  #pragma unroll
  for (int j = 0; j < 8; ++j) a[j] = bf2f((u16)sv[j]);
  int2 nd = ndinfo[node];
  int r0 = nd.x;
  int d  = nd.y;
  int j = 0;
  for (; j + 8 <= d; j += 8){
    bf16x8 v[8];
    #pragma unroll
    for (int u = 0; u < 8; ++u){
      int s = adj[r0 + j + u];
      v[u] = xv[(long)s * 16 + lane];
    }
    #pragma unroll
    for (int q = 0; q < 8; ++q){
      float s01 = bf2f((u16)v[0][q]) + bf2f((u16)v[1][q]);
      float s23 = bf2f((u16)v[2][q]) + bf2f((u16)v[3][q]);
      float s45 = bf2f((u16)v[4][q]) + bf2f((u16)v[5][q]);
      float s67 = bf2f((u16)v[6][q]) + bf2f((u16)v[7][q]);
      a[q] += (s01 + s23) + (s45 + s67);
    }
  }
  for (; j + 4 <= d; j += 4){
    bf16x8 v0 = xv[(long)adj[r0 + j + 0] * 16 + lane];
    bf16x8 v1 = xv[(long)adj[r0 + j + 1] * 16 + lane];
    bf16x8 v2 = xv[(long)adj[r0 + j + 2] * 16 + lane];
    bf16x8 v3 = xv[(long)adj[r0 + j + 3] * 16 + lane];
    #pragma unroll
    for (int q = 0; q < 8; ++q)
      a[q] += (bf2f((u16)v0[q]) + bf2f((u16)v1[q])) + (bf2f((u16)v2[q]) + bf2f((u16)v3[q]));
  }
  for (; j < d; ++j){
    bf16x8 v0 = xv[(long)adj[r0 + j] * 16 + lane];
    #pragma unroll
    for (int q = 0; q < 8; ++q) a[q] += bf2f((u16)v0[q]);
  }
  bf16x8 o;
  #pragma unroll
  for (int j2 = 0; j2 < 8; ++j2) o[j2] = (short)f2bf(a[j2]);
  ((bf16x8*)hb)[(long)node * 16 + lane] = o;
}

// ---------------- fused MLP: Out = relu(BN(relu(A@W1+b1)@W2+b2)) ----------------
// W1 in VGPRs; W2 in swizzled LDS; intermediate bounces through wave-private swizzled LDS.
// Final result ALSO bounces through LDS so global stores are full-line coalesced.
// POOL=1: instead of storing, accumulate per-graph sums into pooled[] (atomics).
template<int POOL>
__global__ __launch_bounds__(256, 3) void k_mlp(const u16* __restrict__ Ain,
                                                const u16* __restrict__ Wt1,
                                                const u16* __restrict__ Wt2,
                                                const float* __restrict__ B1,
                                                const float* __restrict__ SC2,
                                                const float* __restrict__ SH2,
                                                const int* __restrict__ batch,
                                                u16* __restrict__ Out,
                                                float* __restrict__ pooled){
  __shared__ u16 W2s[16384];            // 32 KB, XOR-swizzled
  __shared__ u16 Hs[4][16][128];        // 16 KB, per-wave bounce, XOR-swizzled
  __shared__ float P1[128], P2[128], P3[128];
  int t = threadIdx.x;

  // stage W2 swizzled (2048 chunks of 8 bf16)
  #pragma unroll
  for (int i = 0; i < 8; ++i){
    int c = t + 256 * i;
    int r = c >> 4, cc = c & 15;
    unsigned byte = (unsigned)(r * 256 + cc * 16) ^ (unsigned)((r & 7) << 4);
    *(bf16x8*)((char*)W2s + byte) = *(const bf16x8*)(Wt2 + c * 8);
  }
  if (t < 128){ P1[t] = B1[t]; P2[t] = SC2[t]; P3[t] = SH2[t]; }

  int wv = t >> 6;
  int l  = t & 63;
  int m  = l & 15;
  int kb = l >> 4;

  // W1 fragments in VGPRs
  bf16x8 w1[8][4];
  #pragma unroll
  for (int mt = 0; mt < 8; ++mt)
    #pragma unroll
    for (int ks = 0; ks < 4; ++ks)
      w1[mt][ks] = *(const bf16x8*)(Wt1 + (mt * 16 + m) * 128 + ks * 32 + kb * 8);

  __syncthreads();

  char* hs = (char*)&Hs[wv][0][0];
  unsigned mswz = (unsigned)((m & 7) << 4);
  const int NW = gridDim.x * 4;

  for (int tile = blockIdx.x * 4 + wv; tile < 3125; tile += NW){
    long row0 = (long)tile * 16;
    // ---- GEMM1 ----
    f32x4 acc[8] = {};
    #pragma unroll
    for (int ks = 0; ks < 4; ++ks){
      bf16x8 h = *(const bf16x8*)(Ain + (row0 + m) * 128 + ks * 32 + kb * 8);
      #pragma unroll
      for (int mt = 0; mt < 8; ++mt)
        acc[mt] = __builtin_amdgcn_mfma_f32_16x16x32_bf16(w1[mt][ks], h, acc[mt], 0, 0, 0);
    }
    // ---- epilogue1: relu(acc + b1) -> wave-private swizzled LDS ----
    #pragma unroll
    for (int mt = 0; mt < 8; ++mt){
      int c0 = mt * 16 + kb * 4;
      float4 bb = *(const float4*)&P1[c0];
      ushort4 o;
      o.x = f2bf(fmaxf(acc[mt][0] + bb.x, 0.f));
      o.y = f2bf(fmaxf(acc[mt][1] + bb.y, 0.f));
      o.z = f2bf(fmaxf(acc[mt][2] + bb.z, 0.f));
      o.w = f2bf(fmaxf(acc[mt][3] + bb.w, 0.f));
      unsigned byte = (unsigned)(m * 256 + c0 * 2) ^ mswz;
      *(ushort4*)(hs + byte) = o;
    }
    // ---- GEMM2 (wave-private LDS; compiler inserts lgkmcnt waits) ----
    f32x4 acc2[8] = {};
    #pragma unroll
    for (int ks = 0; ks < 4; ++ks){
      unsigned hb_ = (unsigned)(m * 256 + ks * 64 + kb * 16) ^ mswz;
      bf16x8 h2 = *(const bf16x8*)(hs + hb_);
      #pragma unroll
      for (int mt = 0; mt < 8; ++mt){
        unsigned wb = (unsigned)((mt * 16 + m) * 256 + ks * 64 + kb * 16) ^ mswz;
        bf16x8 w2 = *(const bf16x8*)((char*)W2s + wb);
        acc2[mt] = __builtin_amdgcn_mfma_f32_16x16x32_bf16(w2, h2, acc2[mt], 0, 0, 0);
      }
    }
    // ---- epilogue2: BN + relu ----
    if (!POOL){
      // stage result in wave-private LDS (same swizzle), then store full 64B lines
      #pragma unroll
      for (int mt = 0; mt < 8; ++mt){
        int c0 = mt * 16 + kb * 4;
        float4 sc = *(const float4*)&P2[c0];
        float4 sh = *(const float4*)&P3[c0];
        ushort4 o;
        o.x = f2bf(fmaxf(acc2[mt][0] * sc.x + sh.x, 0.f));
        o.y = f2bf(fmaxf(acc2[mt][1] * sc.y + sh.y, 0.f));
        o.z = f2bf(fmaxf(acc2[mt][2] * sc.z + sh.z, 0.f));
        o.w = f2bf(fmaxf(acc2[mt][3] * sc.w + sh.w, 0.f));
        unsigned byte = (unsigned)(m * 256 + c0 * 2) ^ mswz;
        *(ushort4*)(hs + byte) = o;
      }
      int row = l >> 2;
      unsigned sw = (unsigned)((row & 7) << 4);
      #pragma unroll
      for (int i2 = 0; i2 < 4; ++i2){
        unsigned byte = ((unsigned)(row * 256 + (l & 3) * 16 + i2 * 64)) ^ sw;
        bf16x8 v = *(const bf16x8*)(hs + byte);
        *(bf16x8*)(Out + (row0 + row) * 128 + (l & 3) * 8 + i2 * 32) = v;
      }
    } else {
      int b0 = batch[row0];
      int b15 = batch[row0 + 15];
      if (b0 == b15){
        #pragma unroll
        for (int mt = 0; mt < 8; ++mt){
          int c0 = mt * 16 + kb * 4;
          float4 sc = *(const float4*)&P2[c0];
          float4 sh = *(const float4*)&P3[c0];
          float v0 = fmaxf(acc2[mt][0] * sc.x + sh.x, 0.f);
          float v1 = fmaxf(acc2[mt][1] * sc.y + sh.y, 0.f);
          float v2 = fmaxf(acc2[mt][2] * sc.z + sh.z, 0.f);
          float v3 = fmaxf(acc2[mt][3] * sc.w + sh.w, 0.f);
          #pragma unroll
          for (int off = 1; off < 16; off <<= 1){
            v0 += __shfl_xor(v0, off);
            v1 += __shfl_xor(v1, off);
            v2 += __shfl_xor(v2, off);
            v3 += __shfl_xor(v3, off);
          }
          if (m == 0){
            float* pg = pooled + b0 * 128 + c0;
            atomicAdd(pg + 0, v0); atomicAdd(pg + 1, v1);
            atomicAdd(pg + 2, v2); atomicAdd(pg + 3, v3);
          }
        }
      } else {
        int bm = batch[row0 + m];
        #pragma unroll
        for (int mt = 0; mt < 8; ++mt){
          int c0 = mt * 16 + kb * 4;
          float4 sc = *(const float4*)&P2[c0];
          float4 sh = *(const float4*)&P3[c0];
          float* pg = pooled + bm * 128 + c0;
          atomicAdd(pg + 0, fmaxf(acc2[mt][0] * sc.x + sh.x, 0.f));
          atomicAdd(pg + 1, fmaxf(acc2[mt][1] * sc.y + sh.y, 0.f));
          atomicAdd(pg + 2, fmaxf(acc2[mt][2] * sc.z + sh.z, 0.f));
          atomicAdd(pg + 3, fmaxf(acc2[mt][3] * sc.w + sh.w, 0.f));
        }
      }
    }
  }
}

// ---------------- head: counts via binary search + logits + log_softmax ----------------
__global__ void k_head(const float* __restrict__ pooled, const float* __restrict__ fcw,
                       const float* __restrict__ fcb, const int* __restrict__ batch,
                       float* __restrict__ out){
  int g = threadIdx.x;   // 128 threads, 1 block
  int lo, hi;
  { int a = 0, b = NN; while (a < b){ int mm = (a + b) >> 1; if (batch[mm] < g) a = mm + 1; else b = mm; } lo = a; }
  { int a = lo, b = NN; while (a < b){ int mm = (a + b) >> 1; if (batch[mm] < g + 1) a = mm + 1; else b = mm; } hi = a; }
  float inv = 1.0f / fmaxf((float)(hi - lo), 1.0f);
  float logit[NC];
  #pragma unroll
  for (int c = 0; c < NC; ++c) logit[c] = fcb[c];
  for (int k = 0; k < 128; ++k){
    float pv = pooled[g * 128 + k] * inv;
    #pragma unroll
    for (int c = 0; c < NC; ++c) logit[c] += pv * fcw[k * NC + c];
  }
  float m = logit[0];
  #pragma unroll
  for (int c = 1; c < NC; ++c) m = fmaxf(m, logit[c]);
  float sum = 0.f;
  #pragma unroll
  for (int c = 0; c < NC; ++c) sum += expf(logit[c] - m);
  float ls = logf(sum);
  #pragma unroll
  for (int c = 0; c < NC; ++c) out[g * NC + c] = logit[c] - m - ls;
}

extern "C" void kernel_launch(void* const* d_in, const int* in_sizes, int n_in,
                              void* d_out, int out_size, void* d_ws, size_t ws_size,
                              hipStream_t stream) {
  const float* x     = (const float*)d_in[0];
  const int*   eidx  = (const int*)  d_in[1];
  const int*   batch = (const int*)  d_in[2];
  const float* W1    = (const float*)d_in[3];
  const float* b1    = (const float*)d_in[4];
  const float* W2    = (const float*)d_in[5];
  const float* b2    = (const float*)d_in[6];
  const float* gma   = (const float*)d_in[7];
  const float* bta   = (const float*)d_in[8];
  const float* rmn   = (const float*)d_in[9];
  const float* rvr   = (const float*)d_in[10];
  const float* fcw   = (const float*)d_in[11];
  const float* fcb   = (const float*)d_in[12];
  float* out = (float*)d_out;

  const int* srcI = eidx;          // edge_index[0]
  const int* dstI = eidx + EE;     // edge_index[1]

  // workspace carve
  u16* bufX = (u16*)d_ws;                   // 6.4M u16 each (12.8 MB)
  u16* bufA = bufX + 6400000;
  u16* bufB = bufA + 6400000;
  u16* Wt   = bufB + 6400000;               // 6*16384
  float* SC = (float*)(Wt + 98304);         // 768
  float* SH = SC + 768;                     // 768
  float* pooled = SH + 768;                 // 16384 fp32 (atomic accumulator)
  int* ctr  = (int*)(pooled + 16384);       // scur[64] + bcur[784]
  int* scur = ctr;
  int* bcur = ctr + 64;
  u16* adj  = (u16*)(ctr + 848);            // 782*2560 u16 (padded, bucket-local)
  int2* ndinfo = (int2*)(adj + (BK_N * BK_PAD)); // 50048 (start, deg)
  // staging aliases (dead before bufA/bufB are first written)
  int* sstg = (int*)bufA;                   // 49*36864 ints = 7.2 MB
  int* bstg = (int*)bufB;                   // 784*2560 ints = 8.0 MB

  // zero pooled + counters
  k_zero_int<<<68, 256, 0, stream>>>((int*)pooled, 16384 + 848);

  // CSR build (LDS-staged two-level scatter)
  k_scatL1  <<<NBLK1, 256, 0, stream>>>(srcI, dstI, scur, sstg);
  k_scatL2  <<<SB_N * SLICES, 256, 0, stream>>>(sstg, scur, bcur, bstg);
  k_finalize<<<BK_N, 256, 0, stream>>>(bstg, bcur, adj, ndinfo);

  // fused prep
  k_prep<<<6635, 256, 0, stream>>>(x, W1, W2, b1, b2, gma, bta, rmn, rvr, bufX, Wt, SC, SH);

  // layer schedule:
  // L1: agg X->A ; mlp A->B
  // L2: agg B->A ; mlp A->B
  // L3: agg B->A ; mlp<POOL> A->pooled
  k_agg   <<<3125, 256, 0, stream>>>(bufX, bufA, adj, ndinfo);
  k_mlp<0><<<768, 256, 0, stream>>>(bufA, Wt + 0 * 16384, Wt + 3 * 16384,
                                    SH + 0 * 128, SC + 1 * 128, SH + 1 * 128, batch, bufB, pooled);
  k_agg   <<<3125, 256, 0, stream>>>(bufB, bufA, adj, ndinfo);
  k_mlp<0><<<768, 256, 0, stream>>>(bufA, Wt + 1 * 16384, Wt + 4 * 16384,
                                    SH + 2 * 128, SC + 3 * 128, SH + 3 * 128, batch, bufB, pooled);
  k_agg   <<<3125, 256, 0, stream>>>(bufB, bufA, adj, ndinfo);
  k_mlp<1><<<768, 256, 0, stream>>>(bufA, Wt + 2 * 16384, Wt + 5 * 16384,
                                    SH + 4 * 128, SC + 5 * 128, SH + 5 * 128, batch, bufB, pooled);

  k_head<<<1, 128, 0, stream>>>(pooled, fcw, fcb, batch, out);
}

// Round 8
// 400.280 us; speedup vs baseline: 1.5570x; 1.5570x over previous
//
#include <hip/hip_runtime.h>

#define NN 50000
#define EE 1600000
#define GG 128
#define NC 10

#define SB_N   49      // superbuckets (dst >> 10)
#define SB_PAD 36864   // padded superbucket region (avg 32653)
#define BK_N   782     // 64-node buckets (dst >> 6)
#define BK_PAD 2560    // padded bucket region (avg 2046)
#define CHUNK  4096
#define NBLK1  391     // ceil(EE / CHUNK)
#define SLICES 9       // ceil(SB_PAD / CHUNK)

typedef __attribute__((ext_vector_type(8))) short bf16x8;
typedef __attribute__((ext_vector_type(4))) float f32x4;
typedef unsigned short u16;

__device__ inline u16 f2bf(float x){
  unsigned u = __builtin_bit_cast(unsigned, x);
  u += 0x7fffu + ((u >> 16) & 1u);          // RNE
  return (u16)(u >> 16);
}
__device__ inline float bf2f(u16 u){
  return __builtin_bit_cast(float, ((unsigned)u) << 16);
}

// ---------------- utility ----------------
__global__ void k_zero_int(int* __restrict__ p, int n){
  int i = blockIdx.x * 256 + threadIdx.x;
  if (i < n) p[i] = 0;
}

// ---------------- level-1 scatter: edges -> 49 superbucket regions ----------------
__global__ __launch_bounds__(256) void k_scatL1(const int* __restrict__ srcI, const int* __restrict__ dstI,
                                                int* __restrict__ scur, int* __restrict__ sstg){
  __shared__ int hist[SB_N];
  __shared__ int base[64];
  __shared__ int gadj[SB_N];
  __shared__ unsigned reo[CHUNK];
  int t = threadIdx.x;
  int e0 = blockIdx.x * CHUNK;
  int cnt = EE - e0; if (cnt > CHUNK) cnt = CHUNK;
  if (t < SB_N) hist[t] = 0;
  __syncthreads();
  unsigned p[16]; int rk[16];
  #pragma unroll
  for (int r = 0; r < 16; ++r){
    int i = r * 256 + t;
    if (i < cnt){
      unsigned d = (unsigned)dstI[e0 + i];
      p[r] = (d << 16) | (unsigned)srcI[e0 + i];
      rk[r] = atomicAdd(&hist[d >> 10], 1);
    }
  }
  __syncthreads();
  if (t < 64) base[t] = (t < SB_N) ? hist[t] : 0;
  __syncthreads();
  for (int off = 1; off < 64; off <<= 1){
    int a = (t < 64 && t >= off) ? base[t - off] : 0;
    __syncthreads();
    if (t < 64) base[t] += a;     // inclusive scan
    __syncthreads();
  }
  if (t < SB_N){
    int ex = base[t] - hist[t];   // exclusive
    gadj[t] = atomicAdd(&scur[t], hist[t]) - ex;
  }
  __syncthreads();
  #pragma unroll
  for (int r = 0; r < 16; ++r){
    int i = r * 256 + t;
    if (i < cnt){
      unsigned sb = p[r] >> 26;
      reo[(base[sb] - hist[sb]) + rk[r]] = p[r];
    }
  }
  __syncthreads();
  for (int q = t; q < cnt; q += 256){
    unsigned v = reo[q];
    unsigned sb = v >> 26;
    int off = gadj[sb] + q;       // = gbase + (q - excl)
    if ((unsigned)off < SB_PAD) sstg[sb * SB_PAD + off] = (int)v;
  }
}

// ---------------- level-2 scatter: superbucket -> 16 sub-buckets (64-node) ----------------
__global__ __launch_bounds__(256) void k_scatL2(const int* __restrict__ sstg, const int* __restrict__ scur,
                                                int* __restrict__ bcur, int* __restrict__ bstg){
  __shared__ int hist[16];
  __shared__ int base[16];
  __shared__ int gadj[16];
  __shared__ unsigned reo[CHUNK];
  int t = threadIdx.x;
  int sb = blockIdx.x / SLICES;
  int sl = blockIdx.x % SLICES;
  int ssz = scur[sb]; if (ssz > SB_PAD) ssz = SB_PAD;
  int i0 = sl * CHUNK;
  int cnt = ssz - i0;
  if (cnt <= 0) return;
  if (cnt > CHUNK) cnt = CHUNK;
  if (t < 16) hist[t] = 0;
  __syncthreads();
  unsigned p[16]; int rk[16];
  #pragma unroll
  for (int r = 0; r < 16; ++r){
    int i = r * 256 + t;
    if (i < cnt){
      p[r] = (unsigned)sstg[sb * SB_PAD + i0 + i];
      rk[r] = atomicAdd(&hist[(p[r] >> 22) & 15], 1);
    }
  }
  __syncthreads();
  if (t < 16) base[t] = hist[t];
  __syncthreads();
  for (int off = 1; off < 16; off <<= 1){
    int a = (t < 16 && t >= off) ? base[t - off] : 0;
    __syncthreads();
    if (t < 16) base[t] += a;
    __syncthreads();
  }
  if (t < 16){
    int ex = base[t] - hist[t];
    gadj[t] = atomicAdd(&bcur[sb * 16 + t], hist[t]) - ex;
  }
  __syncthreads();
  #pragma unroll
  for (int r = 0; r < 16; ++r){
    int i = r * 256 + t;
    if (i < cnt){
      unsigned b = (p[r] >> 22) & 15;
      reo[(base[b] - hist[b]) + rk[r]] = p[r];
    }
  }
  __syncthreads();
  for (int q = t; q < cnt; q += 256){
    unsigned v = reo[q];
    unsigned b = (v >> 22) & 15;
    int off = gadj[b] + q;
    if ((unsigned)off < BK_PAD) bstg[(sb * 16 + b) * BK_PAD + off] = (int)v;
  }
}

// ---------------- finalize: per-bucket node grouping -> adj(u16) + ndinfo ----------------
__global__ __launch_bounds__(256) void k_finalize(const int* __restrict__ bstg, const int* __restrict__ bcur,
                                                  u16* __restrict__ adj, int2* __restrict__ ndinfo){
  __shared__ unsigned ebuf[BK_PAD];
  __shared__ int hist[64];
  __shared__ int lrs[64];
  __shared__ int lcur[64];
  int b = blockIdx.x;
  int t = threadIdx.x;
  int bsz = bcur[b]; if (bsz > BK_PAD) bsz = BK_PAD;
  if (t < 64) hist[t] = 0;
  __syncthreads();
  for (int i = t; i < bsz; i += 256){
    unsigned p = (unsigned)bstg[b * BK_PAD + i];
    ebuf[i] = p;
    atomicAdd(&hist[(p >> 16) & 63], 1);
  }
  __syncthreads();
  if (t < 64) lrs[t] = hist[t];
  __syncthreads();
  for (int off = 1; off < 64; off <<= 1){
    int a = (t < 64 && t >= off) ? lrs[t - off] : 0;
    __syncthreads();
    if (t < 64) lrs[t] += a;
    __syncthreads();
  }
  if (t < 64){
    int ex = lrs[t] - hist[t];
    lcur[t] = ex;
    int node = b * 64 + t;
    if (node < NN) ndinfo[node] = make_int2(b * BK_PAD + ex, hist[t]);
  }
  __syncthreads();
  for (int i = t; i < bsz; i += 256){
    unsigned p = ebuf[i];
    int slot = atomicAdd(&lcur[(p >> 16) & 63], 1);
    adj[b * BK_PAD + slot] = (u16)(p & 0xffffu);
  }
}

// ---------------- fused prep: x->bf16 | W->bf16 transposed | BN fold ----------------
__global__ void k_prep(const float* __restrict__ x, const float* __restrict__ W1f, const float* __restrict__ W2f,
                       const float* __restrict__ b1, const float* __restrict__ b2,
                       const float* __restrict__ gma, const float* __restrict__ bta,
                       const float* __restrict__ rmn, const float* __restrict__ rvr,
                       u16* __restrict__ xb, u16* __restrict__ Wt,
                       float* __restrict__ SC, float* __restrict__ SH){
  int bid = blockIdx.x;
  int t = threadIdx.x;
  if (bid < 6250){
    int i = bid * 256 + t;
    float4 v = ((const float4*)x)[i];
    ushort4 o;
    o.x = f2bf(v.x); o.y = f2bf(v.y); o.z = f2bf(v.z); o.w = f2bf(v.w);
    ((ushort4*)xb)[i] = o;
  } else if (bid < 6634){
    int i = (bid - 6250) * 256 + t;       // 0..98303
    int a = i >> 14; int r = i & 16383; int n = r >> 7; int k = r & 127;
    const float* Wsrc = (a < 3) ? (W1f + a * 16384) : (W2f + (a - 3) * 16384);
    Wt[a * 16384 + n * 128 + k] = f2bf(Wsrc[k * 128 + n]);
  } else {
    for (int i = t; i < 768; i += 256){
      int l = i >> 8; int r = i & 255; int mode = r >> 7; int c = r & 127;
      if (mode == 0){
        SC[(l * 2) * 128 + c] = 1.0f;
        SH[(l * 2) * 128 + c] = b1[l * 128 + c];
      } else {
        float S = gma[l * 128 + c] * rsqrtf(rvr[l * 128 + c] + 1e-5f);
        SC[(l * 2 + 1) * 128 + c] = S;
        SH[(l * 2 + 1) * 128 + c] = (b2[l * 128 + c] - rmn[l * 128 + c]) * S + bta[l * 128 + c];
      }
    }
  }
}

// ---------------- aggregation: 16 lanes/node, bf16x8 gathers, 8-deep ----------------
__global__ __launch_bounds__(256) void k_agg(const u16* __restrict__ xb, u16* __restrict__ hb,
                                             const u16* __restrict__ adj,
                                             const int2* __restrict__ ndinfo){
  int t = threadIdx.x;
  int node = blockIdx.x * 16 + (t >> 4);   // grid = 3125 covers NN exactly
  int lane = t & 15;
  const bf16x8* xv = (const bf16x8*)xb;    // 16 bf16x8 per 128-wide row
  bf16x8 sv = xv[(long)node * 16 + lane];
  float a[8];
  #pragma unroll
  for (int j = 0; j < 8; ++j) a[j] = bf2f((u16)sv[j]);
  int2 nd = ndinfo[node];
  int r0 = nd.x;
  int d  = nd.y;
  int j = 0;
  for (; j + 8 <= d; j += 8){
    bf16x8 v[8];
    #pragma unroll
    for (int u = 0; u < 8; ++u){
      int s = adj[r0 + j + u];
      v[u] = xv[(long)s * 16 + lane];
    }
    #pragma unroll
    for (int q = 0; q < 8; ++q){
      float s01 = bf2f((u16)v[0][q]) + bf2f((u16)v[1][q]);
      float s23 = bf2f((u16)v[2][q]) + bf2f((u16)v[3][q]);
      float s45 = bf2f((u16)v[4][q]) + bf2f((u16)v[5][q]);
      float s67 = bf2f((u16)v[6][q]) + bf2f((u16)v[7][q]);
      a[q] += (s01 + s23) + (s45 + s67);
    }
  }
  for (; j + 4 <= d; j += 4){
    bf16x8 v0 = xv[(long)adj[r0 + j + 0] * 16 + lane];
    bf16x8 v1 = xv[(long)adj[r0 + j + 1] * 16 + lane];
    bf16x8 v2 = xv[(long)adj[r0 + j + 2] * 16 + lane];
    bf16x8 v3 = xv[(long)adj[r0 + j + 3] * 16 + lane];
    #pragma unroll
    for (int q = 0; q < 8; ++q)
      a[q] += (bf2f((u16)v0[q]) + bf2f((u16)v1[q])) + (bf2f((u16)v2[q]) + bf2f((u16)v3[q]));
  }
  for (; j < d; ++j){
    bf16x8 v0 = xv[(long)adj[r0 + j] * 16 + lane];
    #pragma unroll
    for (int q = 0; q < 8; ++q) a[q] += bf2f((u16)v0[q]);
  }
  bf16x8 o;
  #pragma unroll
  for (int j2 = 0; j2 < 8; ++j2) o[j2] = (short)f2bf(a[j2]);
  ((bf16x8*)hb)[(long)node * 16 + lane] = o;
}

// ---------------- fused MLP: Out = relu(BN(relu(A@W1+b1)@W2+b2)) ----------------
// 4-wave cooperative tile: wave wv owns output cols [wv*32, wv*32+32) of both GEMMs.
// Weights in VGPRs (64/wave). Intermediate via double-buffered shared swizzled LDS tile.
// POOL=1: accumulate per-graph sums into pooled[] instead of storing.
template<int POOL>
__global__ __launch_bounds__(256, 4) void k_mlp(const u16* __restrict__ Ain,
                                                const u16* __restrict__ Wt1,
                                                const u16* __restrict__ Wt2,
                                                const float* __restrict__ B1,
                                                const float* __restrict__ SC2,
                                                const float* __restrict__ SH2,
                                                const int* __restrict__ batch,
                                                u16* __restrict__ Out,
                                                float* __restrict__ pooled){
  __shared__ u16 Hs[2][16][128];        // 8 KB, XOR-swizzled rows, double-buffered
  __shared__ float P1[128], P2[128], P3[128];
  int t = threadIdx.x;
  if (t < 128){ P1[t] = B1[t]; P2[t] = SC2[t]; P3[t] = SH2[t]; }

  int wv = t >> 6;
  int l  = t & 63;
  int m  = l & 15;
  int kb = l >> 4;
  int mt0 = wv * 2;

  // per-wave weight fragments: 16 x bf16x8 = 64 VGPRs
  bf16x8 w1[2][4], w2[2][4];
  #pragma unroll
  for (int mtl = 0; mtl < 2; ++mtl)
    #pragma unroll
    for (int ks = 0; ks < 4; ++ks){
      w1[mtl][ks] = *(const bf16x8*)(Wt1 + ((mt0 + mtl) * 16 + m) * 128 + ks * 32 + kb * 8);
      w2[mtl][ks] = *(const bf16x8*)(Wt2 + ((mt0 + mtl) * 16 + m) * 128 + ks * 32 + kb * 8);
    }
  __syncthreads();

  unsigned mswz = (unsigned)((m & 7) << 4);

  for (int tile = blockIdx.x; tile < 3125; tile += gridDim.x){
    long row0 = (long)tile * 16;
    char* hs = (char*)&Hs[tile & 1][0][0];
    // ---- GEMM1 (cols mt0*16 .. mt0*16+31) ----
    f32x4 acc0 = {}, acc1 = {};
    #pragma unroll
    for (int ks = 0; ks < 4; ++ks){
      bf16x8 h = *(const bf16x8*)(Ain + (row0 + m) * 128 + ks * 32 + kb * 8);
      acc0 = __builtin_amdgcn_mfma_f32_16x16x32_bf16(w1[0][ks], h, acc0, 0, 0, 0);
      acc1 = __builtin_amdgcn_mfma_f32_16x16x32_bf16(w1[1][ks], h, acc1, 0, 0, 0);
    }
    // ---- epilogue1: relu(acc + b1) -> shared swizzled LDS ----
    #pragma unroll
    for (int mtl = 0; mtl < 2; ++mtl){
      const f32x4& av = mtl ? acc1 : acc0;
      int c0 = (mt0 + mtl) * 16 + kb * 4;
      float4 bb = *(const float4*)&P1[c0];
      ushort4 o;
      o.x = f2bf(fmaxf(av[0] + bb.x, 0.f));
      o.y = f2bf(fmaxf(av[1] + bb.y, 0.f));
      o.z = f2bf(fmaxf(av[2] + bb.z, 0.f));
      o.w = f2bf(fmaxf(av[3] + bb.w, 0.f));
      *(ushort4*)(hs + ((unsigned)(m * 256 + c0 * 2) ^ mswz)) = o;
    }
    __syncthreads();
    // ---- GEMM2 (full k=128 from shared Hs) ----
    f32x4 acc2_0 = {}, acc2_1 = {};
    #pragma unroll
    for (int ks = 0; ks < 4; ++ks){
      bf16x8 h2 = *(const bf16x8*)(hs + ((unsigned)(m * 256 + ks * 64 + kb * 16) ^ mswz));
      acc2_0 = __builtin_amdgcn_mfma_f32_16x16x32_bf16(w2[0][ks], h2, acc2_0, 0, 0, 0);
      acc2_1 = __builtin_amdgcn_mfma_f32_16x16x32_bf16(w2[1][ks], h2, acc2_1, 0, 0, 0);
    }
    // ---- epilogue2: BN + relu ----
    if (!POOL){
      #pragma unroll
      for (int mtl = 0; mtl < 2; ++mtl){
        const f32x4& av = mtl ? acc2_1 : acc2_0;
        int c0 = (mt0 + mtl) * 16 + kb * 4;
        float4 sc = *(const float4*)&P2[c0];
        float4 sh = *(const float4*)&P3[c0];
        ushort4 o;
        o.x = f2bf(fmaxf(av[0] * sc.x + sh.x, 0.f));
        o.y = f2bf(fmaxf(av[1] * sc.y + sh.y, 0.f));
        o.z = f2bf(fmaxf(av[2] * sc.z + sh.z, 0.f));
        o.w = f2bf(fmaxf(av[3] * sc.w + sh.w, 0.f));
        *(ushort4*)(Out + (row0 + m) * 128 + c0) = o;
      }
    } else {
      int b0 = batch[row0];
      int b15 = batch[row0 + 15];
      if (b0 == b15){
        #pragma unroll
        for (int mtl = 0; mtl < 2; ++mtl){
          const f32x4& av = mtl ? acc2_1 : acc2_0;
          int c0 = (mt0 + mtl) * 16 + kb * 4;
          float4 sc = *(const float4*)&P2[c0];
          float4 sh = *(const float4*)&P3[c0];
          float v0 = fmaxf(av[0] * sc.x + sh.x, 0.f);
          float v1 = fmaxf(av[1] * sc.y + sh.y, 0.f);
          float v2 = fmaxf(av[2] * sc.z + sh.z, 0.f);
          float v3 = fmaxf(av[3] * sc.w + sh.w, 0.f);
          #pragma unroll
          for (int off = 1; off < 16; off <<= 1){
            v0 += __shfl_xor(v0, off);
            v1 += __shfl_xor(v1, off);
            v2 += __shfl_xor(v2, off);
            v3 += __shfl_xor(v3, off);
          }
          if (m == 0){
            float* pg = pooled + b0 * 128 + c0;
            atomicAdd(pg + 0, v0); atomicAdd(pg + 1, v1);
            atomicAdd(pg + 2, v2); atomicAdd(pg + 3, v3);
          }
        }
      } else {
        int bm = batch[row0 + m];
        #pragma unroll
        for (int mtl = 0; mtl < 2; ++mtl){
          const f32x4& av = mtl ? acc2_1 : acc2_0;
          int c0 = (mt0 + mtl) * 16 + kb * 4;
          float4 sc = *(const float4*)&P2[c0];
          float4 sh = *(const float4*)&P3[c0];
          float* pg = pooled + bm * 128 + c0;
          atomicAdd(pg + 0, fmaxf(av[0] * sc.x + sh.x, 0.f));
          atomicAdd(pg + 1, fmaxf(av[1] * sc.y + sh.y, 0.f));
          atomicAdd(pg + 2, fmaxf(av[2] * sc.z + sh.z, 0.f));
          atomicAdd(pg + 3, fmaxf(av[3] * sc.w + sh.w, 0.f));
        }
      }
    }
  }
}

// ---------------- head: counts via binary search + logits + log_softmax ----------------
__global__ void k_head(const float* __restrict__ pooled, const float* __restrict__ fcw,
                       const float* __restrict__ fcb, const int* __restrict__ batch,
                       float* __restrict__ out){
  int g = threadIdx.x;   // 128 threads, 1 block
  int lo, hi;
  { int a = 0, b = NN; while (a < b){ int mm = (a + b) >> 1; if (batch[mm] < g) a = mm + 1; else b = mm; } lo = a; }
  { int a = lo, b = NN; while (a < b){ int mm = (a + b) >> 1; if (batch[mm] < g + 1) a = mm + 1; else b = mm; } hi = a; }
  float inv = 1.0f / fmaxf((float)(hi - lo), 1.0f);
  float logit[NC];
  #pragma unroll
  for (int c = 0; c < NC; ++c) logit[c] = fcb[c];
  for (int k = 0; k < 128; ++k){
    float pv = pooled[g * 128 + k] * inv;
    #pragma unroll
    for (int c = 0; c < NC; ++c) logit[c] += pv * fcw[k * NC + c];
  }
  float m = logit[0];
  #pragma unroll
  for (int c = 1; c < NC; ++c) m = fmaxf(m, logit[c]);
  float sum = 0.f;
  #pragma unroll
  for (int c = 0; c < NC; ++c) sum += expf(logit[c] - m);
  float ls = logf(sum);
  #pragma unroll
  for (int c = 0; c < NC; ++c) out[g * NC + c] = logit[c] - m - ls;
}

extern "C" void kernel_launch(void* const* d_in, const int* in_sizes, int n_in,
                              void* d_out, int out_size, void* d_ws, size_t ws_size,
                              hipStream_t stream) {
  const float* x     = (const float*)d_in[0];
  const int*   eidx  = (const int*)  d_in[1];
  const int*   batch = (const int*)  d_in[2];
  const float* W1    = (const float*)d_in[3];
  const float* b1    = (const float*)d_in[4];
  const float* W2    = (const float*)d_in[5];
  const float* b2    = (const float*)d_in[6];
  const float* gma   = (const float*)d_in[7];
  const float* bta   = (const float*)d_in[8];
  const float* rmn   = (const float*)d_in[9];
  const float* rvr   = (const float*)d_in[10];
  const float* fcw   = (const float*)d_in[11];
  const float* fcb   = (const float*)d_in[12];
  float* out = (float*)d_out;

  const int* srcI = eidx;          // edge_index[0]
  const int* dstI = eidx + EE;     // edge_index[1]

  // workspace carve
  u16* bufX = (u16*)d_ws;                   // 6.4M u16 each (12.8 MB)
  u16* bufA = bufX + 6400000;
  u16* bufB = bufA + 6400000;
  u16* Wt   = bufB + 6400000;               // 6*16384
  float* SC = (float*)(Wt + 98304);         // 768
  float* SH = SC + 768;                     // 768
  float* pooled = SH + 768;                 // 16384 fp32 (atomic accumulator)
  int* ctr  = (int*)(pooled + 16384);       // scur[64] + bcur[784]
  int* scur = ctr;
  int* bcur = ctr + 64;
  u16* adj  = (u16*)(ctr + 848);            // 782*2560 u16 (padded, bucket-local)
  int2* ndinfo = (int2*)(adj + (BK_N * BK_PAD)); // 50048 (start, deg)
  // staging aliases (dead before bufA/bufB are first written)
  int* sstg = (int*)bufA;                   // 49*36864 ints = 7.2 MB
  int* bstg = (int*)bufB;                   // 784*2560 ints = 8.0 MB

  // zero pooled + counters
  k_zero_int<<<68, 256, 0, stream>>>((int*)pooled, 16384 + 848);

  // CSR build (LDS-staged two-level scatter)
  k_scatL1  <<<NBLK1, 256, 0, stream>>>(srcI, dstI, scur, sstg);
  k_scatL2  <<<SB_N * SLICES, 256, 0, stream>>>(sstg, scur, bcur, bstg);
  k_finalize<<<BK_N, 256, 0, stream>>>(bstg, bcur, adj, ndinfo);

  // fused prep
  k_prep<<<6635, 256, 0, stream>>>(x, W1, W2, b1, b2, gma, bta, rmn, rvr, bufX, Wt, SC, SH);

  // layer schedule:
  // L1: agg X->A ; mlp A->B
  // L2: agg B->A ; mlp A->B
  // L3: agg B->A ; mlp<POOL> A->pooled
  k_agg   <<<3125, 256, 0, stream>>>(bufX, bufA, adj, ndinfo);
  k_mlp<0><<<1024, 256, 0, stream>>>(bufA, Wt + 0 * 16384, Wt + 3 * 16384,
                                     SH + 0 * 128, SC + 1 * 128, SH + 1 * 128, batch, bufB, pooled);
  k_agg   <<<3125, 256, 0, stream>>>(bufB, bufA, adj, ndinfo);
  k_mlp<0><<<1024, 256, 0, stream>>>(bufA, Wt + 1 * 16384, Wt + 4 * 16384,
                                     SH + 2 * 128, SC + 3 * 128, SH + 3 * 128, batch, bufB, pooled);
  k_agg   <<<3125, 256, 0, stream>>>(bufB, bufA, adj, ndinfo);
  k_mlp<1><<<1024, 256, 0, stream>>>(bufA, Wt + 2 * 16384, Wt + 5 * 16384,
                                     SH + 4 * 128, SC + 5 * 128, SH + 5 * 128, batch, bufB, pooled);

  k_head<<<1, 128, 0, stream>>>(pooled, fcw, fcb, batch, out);
}

// Round 9
// 391.144 us; speedup vs baseline: 1.5934x; 1.0234x over previous
//
#include <hip/hip_runtime.h>

#define NN 50000
#define EE 1600000
#define GG 128
#define NC 10

#define SB_N   49      // superbuckets (dst >> 10)
#define SB_PAD 36864   // padded superbucket region (avg 32653)
#define BK_N   782     // 64-node buckets (dst >> 6)
#define BK_PAD 2560    // padded bucket region (avg 2046)
#define CHUNK  4096
#define NBLK1  391     // ceil(EE / CHUNK)
#define SLICES 9       // ceil(SB_PAD / CHUNK)

typedef __attribute__((ext_vector_type(8))) short bf16x8;
typedef __attribute__((ext_vector_type(4))) float f32x4;
typedef unsigned short u16;

__device__ inline u16 f2bf(float x){
  unsigned u = __builtin_bit_cast(unsigned, x);
  u += 0x7fffu + ((u >> 16) & 1u);          // RNE
  return (u16)(u >> 16);
}
__device__ inline float bf2f(u16 u){
  return __builtin_bit_cast(float, ((unsigned)u) << 16);
}

// ---------------- utility ----------------
__global__ void k_zero_int(int* __restrict__ p, int n){
  int i = blockIdx.x * 256 + threadIdx.x;
  if (i < n) p[i] = 0;
}

// ---------------- level-1 scatter: edges -> 49 superbucket regions ----------------
__global__ __launch_bounds__(256) void k_scatL1(const int* __restrict__ srcI, const int* __restrict__ dstI,
                                                int* __restrict__ scur, int* __restrict__ sstg){
  __shared__ int hist[SB_N];
  __shared__ int base[64];
  __shared__ int gadj[SB_N];
  __shared__ unsigned reo[CHUNK];
  int t = threadIdx.x;
  int e0 = blockIdx.x * CHUNK;
  int cnt = EE - e0; if (cnt > CHUNK) cnt = CHUNK;
  if (t < SB_N) hist[t] = 0;
  __syncthreads();
  unsigned p[16]; int rk[16];
  #pragma unroll
  for (int r = 0; r < 16; ++r){
    int i = r * 256 + t;
    if (i < cnt){
      unsigned d = (unsigned)dstI[e0 + i];
      p[r] = (d << 16) | (unsigned)srcI[e0 + i];
      rk[r] = atomicAdd(&hist[d >> 10], 1);
    }
  }
  __syncthreads();
  if (t < 64) base[t] = (t < SB_N) ? hist[t] : 0;
  __syncthreads();
  for (int off = 1; off < 64; off <<= 1){
    int a = (t < 64 && t >= off) ? base[t - off] : 0;
    __syncthreads();
    if (t < 64) base[t] += a;     // inclusive scan
    __syncthreads();
  }
  if (t < SB_N){
    int ex = base[t] - hist[t];   // exclusive
    gadj[t] = atomicAdd(&scur[t], hist[t]) - ex;
  }
  __syncthreads();
  #pragma unroll
  for (int r = 0; r < 16; ++r){
    int i = r * 256 + t;
    if (i < cnt){
      unsigned sb = p[r] >> 26;
      reo[(base[sb] - hist[sb]) + rk[r]] = p[r];
    }
  }
  __syncthreads();
  for (int q = t; q < cnt; q += 256){
    unsigned v = reo[q];
    unsigned sb = v >> 26;
    int off = gadj[sb] + q;       // = gbase + (q - excl)
    if ((unsigned)off < SB_PAD) sstg[sb * SB_PAD + off] = (int)v;
  }
}

// ---------------- level-2 scatter: superbucket -> 16 sub-buckets (64-node) ----------------
__global__ __launch_bounds__(256) void k_scatL2(const int* __restrict__ sstg, const int* __restrict__ scur,
                                                int* __restrict__ bcur, int* __restrict__ bstg){
  __shared__ int hist[16];
  __shared__ int base[16];
  __shared__ int gadj[16];
  __shared__ unsigned reo[CHUNK];
  int t = threadIdx.x;
  int sb = blockIdx.x / SLICES;
  int sl = blockIdx.x % SLICES;
  int ssz = scur[sb]; if (ssz > SB_PAD) ssz = SB_PAD;
  int i0 = sl * CHUNK;
  int cnt = ssz - i0;
  if (cnt <= 0) return;
  if (cnt > CHUNK) cnt = CHUNK;
  if (t < 16) hist[t] = 0;
  __syncthreads();
  unsigned p[16]; int rk[16];
  #pragma unroll
  for (int r = 0; r < 16; ++r){
    int i = r * 256 + t;
    if (i < cnt){
      p[r] = (unsigned)sstg[sb * SB_PAD + i0 + i];
      rk[r] = atomicAdd(&hist[(p[r] >> 22) & 15], 1);
    }
  }
  __syncthreads();
  if (t < 16) base[t] = hist[t];
  __syncthreads();
  for (int off = 1; off < 16; off <<= 1){
    int a = (t < 16 && t >= off) ? base[t - off] : 0;
    __syncthreads();
    if (t < 16) base[t] += a;
    __syncthreads();
  }
  if (t < 16){
    int ex = base[t] - hist[t];
    gadj[t] = atomicAdd(&bcur[sb * 16 + t], hist[t]) - ex;
  }
  __syncthreads();
  #pragma unroll
  for (int r = 0; r < 16; ++r){
    int i = r * 256 + t;
    if (i < cnt){
      unsigned b = (p[r] >> 22) & 15;
      reo[(base[b] - hist[b]) + rk[r]] = p[r];
    }
  }
  __syncthreads();
  for (int q = t; q < cnt; q += 256){
    unsigned v = reo[q];
    unsigned b = (v >> 22) & 15;
    int off = gadj[b] + q;
    if ((unsigned)off < BK_PAD) bstg[(sb * 16 + b) * BK_PAD + off] = (int)v;
  }
}

// ---------------- finalize: per-bucket node grouping -> adj(u16) + ndinfo ----------------
__global__ __launch_bounds__(256) void k_finalize(const int* __restrict__ bstg, const int* __restrict__ bcur,
                                                  u16* __restrict__ adj, int2* __restrict__ ndinfo){
  __shared__ unsigned ebuf[BK_PAD];
  __shared__ int hist[64];
  __shared__ int lrs[64];
  __shared__ int lcur[64];
  int b = blockIdx.x;
  int t = threadIdx.x;
  int bsz = bcur[b]; if (bsz > BK_PAD) bsz = BK_PAD;
  if (t < 64) hist[t] = 0;
  __syncthreads();
  for (int i = t; i < bsz; i += 256){
    unsigned p = (unsigned)bstg[b * BK_PAD + i];
    ebuf[i] = p;
    atomicAdd(&hist[(p >> 16) & 63], 1);
  }
  __syncthreads();
  if (t < 64) lrs[t] = hist[t];
  __syncthreads();
  for (int off = 1; off < 64; off <<= 1){
    int a = (t < 64 && t >= off) ? lrs[t - off] : 0;
    __syncthreads();
    if (t < 64) lrs[t] += a;
    __syncthreads();
  }
  if (t < 64){
    int ex = lrs[t] - hist[t];
    lcur[t] = ex;
    int node = b * 64 + t;
    if (node < NN) ndinfo[node] = make_int2(b * BK_PAD + ex, hist[t]);
  }
  __syncthreads();
  for (int i = t; i < bsz; i += 256){
    unsigned p = ebuf[i];
    int slot = atomicAdd(&lcur[(p >> 16) & 63], 1);
    adj[b * BK_PAD + slot] = (u16)(p & 0xffffu);
  }
}

// ---------------- fused prep: x->bf16 | W->bf16 transposed | BN fold ----------------
__global__ void k_prep(const float* __restrict__ x, const float* __restrict__ W1f, const float* __restrict__ W2f,
                       const float* __restrict__ b1, const float* __restrict__ b2,
                       const float* __restrict__ gma, const float* __restrict__ bta,
                       const float* __restrict__ rmn, const float* __restrict__ rvr,
                       u16* __restrict__ xb, u16* __restrict__ Wt,
                       float* __restrict__ SC, float* __restrict__ SH){
  int bid = blockIdx.x;
  int t = threadIdx.x;
  if (bid < 6250){
    int i = bid * 256 + t;
    float4 v = ((const float4*)x)[i];
    ushort4 o;
    o.x = f2bf(v.x); o.y = f2bf(v.y); o.z = f2bf(v.z); o.w = f2bf(v.w);
    ((ushort4*)xb)[i] = o;
  } else if (bid < 6634){
    int i = (bid - 6250) * 256 + t;       // 0..98303
    int a = i >> 14; int r = i & 16383; int n = r >> 7; int k = r & 127;
    const float* Wsrc = (a < 3) ? (W1f + a * 16384) : (W2f + (a - 3) * 16384);
    Wt[a * 16384 + n * 128 + k] = f2bf(Wsrc[k * 128 + n]);
  } else {
    for (int i = t; i < 768; i += 256){
      int l = i >> 8; int r = i & 255; int mode = r >> 7; int c = r & 127;
      if (mode == 0){
        SC[(l * 2) * 128 + c] = 1.0f;
        SH[(l * 2) * 128 + c] = b1[l * 128 + c];
      } else {
        float S = gma[l * 128 + c] * rsqrtf(rvr[l * 128 + c] + 1e-5f);
        SC[(l * 2 + 1) * 128 + c] = S;
        SH[(l * 2 + 1) * 128 + c] = (b2[l * 128 + c] - rmn[l * 128 + c]) * S + bta[l * 128 + c];
      }
    }
  }
}

// ---------------- aggregation: 16 lanes/node, bf16x8 gathers, 8-deep ----------------
__global__ __launch_bounds__(256) void k_agg(const u16* __restrict__ xb, u16* __restrict__ hb,
                                             const u16* __restrict__ adj,
                                             const int2* __restrict__ ndinfo){
  int t = threadIdx.x;
  int node = blockIdx.x * 16 + (t >> 4);   // grid = 3125 covers NN exactly
  int lane = t & 15;
  const bf16x8* xv = (const bf16x8*)xb;    // 16 bf16x8 per 128-wide row
  bf16x8 sv = xv[(long)node * 16 + lane];
  float a[8];
  #pragma unroll
  for (int j = 0; j < 8; ++j) a[j] = bf2f((u16)sv[j]);
  int2 nd = ndinfo[node];
  int r0 = nd.x;
  int d  = nd.y;
  int j = 0;
  for (; j + 8 <= d; j += 8){
    bf16x8 v[8];
    #pragma unroll
    for (int u = 0; u < 8; ++u){
      int s = adj[r0 + j + u];
      v[u] = xv[(long)s * 16 + lane];
    }
    #pragma unroll
    for (int q = 0; q < 8; ++q){
      float s01 = bf2f((u16)v[0][q]) + bf2f((u16)v[1][q]);
      float s23 = bf2f((u16)v[2][q]) + bf2f((u16)v[3][q]);
      float s45 = bf2f((u16)v[4][q]) + bf2f((u16)v[5][q]);
      float s67 = bf2f((u16)v[6][q]) + bf2f((u16)v[7][q]);
      a[q] += (s01 + s23) + (s45 + s67);
    }
  }
  for (; j + 4 <= d; j += 4){
    bf16x8 v0 = xv[(long)adj[r0 + j + 0] * 16 + lane];
    bf16x8 v1 = xv[(long)adj[r0 + j + 1] * 16 + lane];
    bf16x8 v2 = xv[(long)adj[r0 + j + 2] * 16 + lane];
    bf16x8 v3 = xv[(long)adj[r0 + j + 3] * 16 + lane];
    #pragma unroll
    for (int q = 0; q < 8; ++q)
      a[q] += (bf2f((u16)v0[q]) + bf2f((u16)v1[q])) + (bf2f((u16)v2[q]) + bf2f((u16)v3[q]));
  }
  for (; j < d; ++j){
    bf16x8 v0 = xv[(long)adj[r0 + j] * 16 + lane];
    #pragma unroll
    for (int q = 0; q < 8; ++q) a[q] += bf2f((u16)v0[q]);
  }
  bf16x8 o;
  #pragma unroll
  for (int j2 = 0; j2 < 8; ++j2) o[j2] = (short)f2bf(a[j2]);
  ((bf16x8*)hb)[(long)node * 16 + lane] = o;
}

// ---------------- fused MLP: Out = relu(BN(relu(A@W1+b1)@W2+b2)) ----------------
// 4-wave cooperative tile; weights PINNED in VGPRs (asm keep-live); input prefetch
// into dead h regs after GEMM1; double-buffered shared Hs with per-iter toggle.
// POOL=1: accumulate per-graph sums into pooled[] instead of storing.
template<int POOL>
__global__ __launch_bounds__(256, 3) void k_mlp(const u16* __restrict__ Ain,
                                                const u16* __restrict__ Wt1,
                                                const u16* __restrict__ Wt2,
                                                const float* __restrict__ B1,
                                                const float* __restrict__ SC2,
                                                const float* __restrict__ SH2,
                                                const int* __restrict__ batch,
                                                u16* __restrict__ Out,
                                                float* __restrict__ pooled){
  __shared__ u16 Hs[2][16][128];        // 8 KB, XOR-swizzled rows, double-buffered
  __shared__ float P1[128], P2[128], P3[128];
  int t = threadIdx.x;
  if (t < 128){ P1[t] = B1[t]; P2[t] = SC2[t]; P3[t] = SH2[t]; }

  int wv = t >> 6;
  int l  = t & 63;
  int m  = l & 15;
  int kb = l >> 4;
  int mt0 = wv * 2;

  // per-wave weight fragments: 16 x bf16x8 = 64 VGPRs, pinned
  bf16x8 w1[2][4], w2[2][4];
  #pragma unroll
  for (int mtl = 0; mtl < 2; ++mtl)
    #pragma unroll
    for (int ks = 0; ks < 4; ++ks){
      w1[mtl][ks] = *(const bf16x8*)(Wt1 + ((mt0 + mtl) * 16 + m) * 128 + ks * 32 + kb * 8);
      w2[mtl][ks] = *(const bf16x8*)(Wt2 + ((mt0 + mtl) * 16 + m) * 128 + ks * 32 + kb * 8);
    }
  #pragma unroll
  for (int mtl = 0; mtl < 2; ++mtl)
    #pragma unroll
    for (int ks = 0; ks < 4; ++ks){
      asm volatile("" : "+v"(w1[mtl][ks]));
      asm volatile("" : "+v"(w2[mtl][ks]));
    }
  __syncthreads();

  unsigned mswz = (unsigned)((m & 7) << 4);
  int tile = blockIdx.x;
  bf16x8 h[4];
  if (tile < 3125){
    long r = (long)tile * 16 + m;
    #pragma unroll
    for (int ks = 0; ks < 4; ++ks) h[ks] = *(const bf16x8*)(Ain + r * 128 + ks * 32 + kb * 8);
  }
  int buf = 0;

  while (tile < 3125){
    long row0 = (long)tile * 16;
    char* hs = (char*)&Hs[buf][0][0];
    // ---- GEMM1 (cols mt0*16 .. mt0*16+31) ----
    f32x4 acc0 = {}, acc1 = {};
    #pragma unroll
    for (int ks = 0; ks < 4; ++ks){
      acc0 = __builtin_amdgcn_mfma_f32_16x16x32_bf16(w1[0][ks], h[ks], acc0, 0, 0, 0);
      acc1 = __builtin_amdgcn_mfma_f32_16x16x32_bf16(w1[1][ks], h[ks], acc1, 0, 0, 0);
    }
    // ---- prefetch next tile's input into (now dead) h regs ----
    int ntile = tile + gridDim.x;
    if (ntile < 3125){
      long r = (long)ntile * 16 + m;
      #pragma unroll
      for (int ks = 0; ks < 4; ++ks) h[ks] = *(const bf16x8*)(Ain + r * 128 + ks * 32 + kb * 8);
    }
    // ---- epilogue1: relu(acc + b1) -> shared swizzled LDS ----
    #pragma unroll
    for (int mtl = 0; mtl < 2; ++mtl){
      const f32x4& av = mtl ? acc1 : acc0;
      int c0 = (mt0 + mtl) * 16 + kb * 4;
      float4 bb = *(const float4*)&P1[c0];
      ushort4 o;
      o.x = f2bf(fmaxf(av[0] + bb.x, 0.f));
      o.y = f2bf(fmaxf(av[1] + bb.y, 0.f));
      o.z = f2bf(fmaxf(av[2] + bb.z, 0.f));
      o.w = f2bf(fmaxf(av[3] + bb.w, 0.f));
      *(ushort4*)(hs + ((unsigned)(m * 256 + c0 * 2) ^ mswz)) = o;
    }
    __syncthreads();
    // ---- GEMM2 (full k=128 from shared Hs) ----
    f32x4 acc2_0 = {}, acc2_1 = {};
    #pragma unroll
    for (int ks = 0; ks < 4; ++ks){
      bf16x8 h2 = *(const bf16x8*)(hs + ((unsigned)(m * 256 + ks * 64 + kb * 16) ^ mswz));
      acc2_0 = __builtin_amdgcn_mfma_f32_16x16x32_bf16(w2[0][ks], h2, acc2_0, 0, 0, 0);
      acc2_1 = __builtin_amdgcn_mfma_f32_16x16x32_bf16(w2[1][ks], h2, acc2_1, 0, 0, 0);
    }
    // ---- epilogue2: BN + relu ----
    if (!POOL){
      #pragma unroll
      for (int mtl = 0; mtl < 2; ++mtl){
        const f32x4& av = mtl ? acc2_1 : acc2_0;
        int c0 = (mt0 + mtl) * 16 + kb * 4;
        float4 sc = *(const float4*)&P2[c0];
        float4 sh = *(const float4*)&P3[c0];
        ushort4 o;
        o.x = f2bf(fmaxf(av[0] * sc.x + sh.x, 0.f));
        o.y = f2bf(fmaxf(av[1] * sc.y + sh.y, 0.f));
        o.z = f2bf(fmaxf(av[2] * sc.z + sh.z, 0.f));
        o.w = f2bf(fmaxf(av[3] * sc.w + sh.w, 0.f));
        *(ushort4*)(Out + (row0 + m) * 128 + c0) = o;
      }
    } else {
      int b0 = batch[row0];
      int b15 = batch[row0 + 15];
      if (b0 == b15){
        #pragma unroll
        for (int mtl = 0; mtl < 2; ++mtl){
          const f32x4& av = mtl ? acc2_1 : acc2_0;
          int c0 = (mt0 + mtl) * 16 + kb * 4;
          float4 sc = *(const float4*)&P2[c0];
          float4 sh = *(const float4*)&P3[c0];
          float v0 = fmaxf(av[0] * sc.x + sh.x, 0.f);
          float v1 = fmaxf(av[1] * sc.y + sh.y, 0.f);
          float v2 = fmaxf(av[2] * sc.z + sh.z, 0.f);
          float v3 = fmaxf(av[3] * sc.w + sh.w, 0.f);
          #pragma unroll
          for (int off = 1; off < 16; off <<= 1){
            v0 += __shfl_xor(v0, off);
            v1 += __shfl_xor(v1, off);
            v2 += __shfl_xor(v2, off);
            v3 += __shfl_xor(v3, off);
          }
          if (m == 0){
            float* pg = pooled + b0 * 128 + c0;
            atomicAdd(pg + 0, v0); atomicAdd(pg + 1, v1);
            atomicAdd(pg + 2, v2); atomicAdd(pg + 3, v3);
          }
        }
      } else {
        int bm = batch[row0 + m];
        #pragma unroll
        for (int mtl = 0; mtl < 2; ++mtl){
          const f32x4& av = mtl ? acc2_1 : acc2_0;
          int c0 = (mt0 + mtl) * 16 + kb * 4;
          float4 sc = *(const float4*)&P2[c0];
          float4 sh = *(const float4*)&P3[c0];
          float* pg = pooled + bm * 128 + c0;
          atomicAdd(pg + 0, fmaxf(av[0] * sc.x + sh.x, 0.f));
          atomicAdd(pg + 1, fmaxf(av[1] * sc.y + sh.y, 0.f));
          atomicAdd(pg + 2, fmaxf(av[2] * sc.z + sh.z, 0.f));
          atomicAdd(pg + 3, fmaxf(av[3] * sc.w + sh.w, 0.f));
        }
      }
    }
    tile = ntile;
    buf ^= 1;
  }
}

// ---------------- head: counts via binary search + logits + log_softmax ----------------
__global__ void k_head(const float* __restrict__ pooled, const float* __restrict__ fcw,
                       const float* __restrict__ fcb, const int* __restrict__ batch,
                       float* __restrict__ out){
  int g = threadIdx.x;   // 128 threads, 1 block
  int lo, hi;
  { int a = 0, b = NN; while (a < b){ int mm = (a + b) >> 1; if (batch[mm] < g) a = mm + 1; else b = mm; } lo = a; }
  { int a = lo, b = NN; while (a < b){ int mm = (a + b) >> 1; if (batch[mm] < g + 1) a = mm + 1; else b = mm; } hi = a; }
  float inv = 1.0f / fmaxf((float)(hi - lo), 1.0f);
  float logit[NC];
  #pragma unroll
  for (int c = 0; c < NC; ++c) logit[c] = fcb[c];
  for (int k = 0; k < 128; ++k){
    float pv = pooled[g * 128 + k] * inv;
    #pragma unroll
    for (int c = 0; c < NC; ++c) logit[c] += pv * fcw[k * NC + c];
  }
  float m = logit[0];
  #pragma unroll
  for (int c = 1; c < NC; ++c) m = fmaxf(m, logit[c]);
  float sum = 0.f;
  #pragma unroll
  for (int c = 0; c < NC; ++c) sum += expf(logit[c] - m);
  float ls = logf(sum);
  #pragma unroll
  for (int c = 0; c < NC; ++c) out[g * NC + c] = logit[c] - m - ls;
}

extern "C" void kernel_launch(void* const* d_in, const int* in_sizes, int n_in,
                              void* d_out, int out_size, void* d_ws, size_t ws_size,
                              hipStream_t stream) {
  const float* x     = (const float*)d_in[0];
  const int*   eidx  = (const int*)  d_in[1];
  const int*   batch = (const int*)  d_in[2];
  const float* W1    = (const float*)d_in[3];
  const float* b1    = (const float*)d_in[4];
  const float* W2    = (const float*)d_in[5];
  const float* b2    = (const float*)d_in[6];
  const float* gma   = (const float*)d_in[7];
  const float* bta   = (const float*)d_in[8];
  const float* rmn   = (const float*)d_in[9];
  const float* rvr   = (const float*)d_in[10];
  const float* fcw   = (const float*)d_in[11];
  const float* fcb   = (const float*)d_in[12];
  float* out = (float*)d_out;

  const int* srcI = eidx;          // edge_index[0]
  const int* dstI = eidx + EE;     // edge_index[1]

  // workspace carve
  u16* bufX = (u16*)d_ws;                   // 6.4M u16 each (12.8 MB)
  u16* bufA = bufX + 6400000;
  u16* bufB = bufA + 6400000;
  u16* Wt   = bufB + 6400000;               // 6*16384
  float* SC = (float*)(Wt + 98304);         // 768
  float* SH = SC + 768;                     // 768
  float* pooled = SH + 768;                 // 16384 fp32 (atomic accumulator)
  int* ctr  = (int*)(pooled + 16384);       // scur[64] + bcur[784]
  int* scur = ctr;
  int* bcur = ctr + 64;
  u16* adj  = (u16*)(ctr + 848);            // 782*2560 u16 (padded, bucket-local)
  int2* ndinfo = (int2*)(adj + (BK_N * BK_PAD)); // 50048 (start, deg)
  // staging aliases (dead before bufA/bufB are first written)
  int* sstg = (int*)bufA;                   // 49*36864 ints = 7.2 MB
  int* bstg = (int*)bufB;                   // 784*2560 ints = 8.0 MB

  // zero pooled + counters
  k_zero_int<<<68, 256, 0, stream>>>((int*)pooled, 16384 + 848);

  // CSR build (LDS-staged two-level scatter)
  k_scatL1  <<<NBLK1, 256, 0, stream>>>(srcI, dstI, scur, sstg);
  k_scatL2  <<<SB_N * SLICES, 256, 0, stream>>>(sstg, scur, bcur, bstg);
  k_finalize<<<BK_N, 256, 0, stream>>>(bstg, bcur, adj, ndinfo);

  // fused prep
  k_prep<<<6635, 256, 0, stream>>>(x, W1, W2, b1, b2, gma, bta, rmn, rvr, bufX, Wt, SC, SH);

  // layer schedule:
  // L1: agg X->A ; mlp A->B
  // L2: agg B->A ; mlp A->B
  // L3: agg B->A ; mlp<POOL> A->pooled
  k_agg   <<<3125, 256, 0, stream>>>(bufX, bufA, adj, ndinfo);
  k_mlp<0><<<768, 256, 0, stream>>>(bufA, Wt + 0 * 16384, Wt + 3 * 16384,
                                    SH + 0 * 128, SC + 1 * 128, SH + 1 * 128, batch, bufB, pooled);
  k_agg   <<<3125, 256, 0, stream>>>(bufB, bufA, adj, ndinfo);
  k_mlp<0><<<768, 256, 0, stream>>>(bufA, Wt + 1 * 16384, Wt + 4 * 16384,
                                    SH + 2 * 128, SC + 3 * 128, SH + 3 * 128, batch, bufB, pooled);
  k_agg   <<<3125, 256, 0, stream>>>(bufB, bufA, adj, ndinfo);
  k_mlp<1><<<768, 256, 0, stream>>>(bufA, Wt + 2 * 16384, Wt + 5 * 16384,
                                    SH + 4 * 128, SC + 5 * 128, SH + 5 * 128, batch, bufB, pooled);

  k_head<<<1, 128, 0, stream>>>(pooled, fcw, fcb, batch, out);
}